// Round 3
// baseline (119.779 us; speedup 1.0000x reference)
//
#include <hip/hip_runtime.h>

#define BB 256
#define SS 512
#define DD 64
#define LN_EPS 1e-5f
#define L2E 1.4426950408889634f

typedef float v2f __attribute__((ext_vector_type(2)));

__device__ __forceinline__ float fexp2(float x) {
#if __has_builtin(__builtin_amdgcn_exp2f)
    return __builtin_amdgcn_exp2f(x);
#else
    float r; asm("v_exp_f32 %0, %1" : "=v"(r) : "v"(x)); return r;
#endif
}

// One fused kernel: 768 blocks (B x 3 tasks) x 512 threads.
// Each block redundantly computes its type's prep constants (cheap, L2-hot
// weights, overlapped across blocks), then runs the 512-key exp2 loop.
//
// Algebra: h = x*pw + pb (rank-1+const) propagates to
//   attn[q,k] = softmax_k((alpha*x_q + gamma)*y_k)
//   row result r_q = x_q*pw + t_q*u + e,  t_q = sum_k attn*y_k (scalar!)
//   LN closed-form via 3x3 Gram of centered {pw,u,e}; seq-mean needs only
//   P=mean(x*inv), T=mean(t*inv), I=mean(inv).
__global__ __launch_bounds__(512, 6) void fused_kernel(
    const float* __restrict__ x_src, const float* __restrict__ x_tgt,
    const float* __restrict__ proj_w, const float* __restrict__ proj_b,
    const float* __restrict__ sa_in_w, const float* __restrict__ sa_in_b,
    const float* __restrict__ sa_out_w, const float* __restrict__ sa_out_b,
    const float* __restrict__ sa_ln_g, const float* __restrict__ sa_ln_b,
    const float* __restrict__ ca_in_w, const float* __restrict__ ca_in_b,
    const float* __restrict__ ca_out_w, const float* __restrict__ ca_out_b,
    const float* __restrict__ ca_ln_g, const float* __restrict__ ca_ln_b,
    float* __restrict__ out)
{
    const int tid  = threadIdx.x;
    const int b    = blockIdx.x / 3;
    const int task = blockIdx.x % 3;
    // task 0: sa_src (x=xs,y=xs) -> z_src_private @ B*D
    // task 1: sa_tgt (x=xt,y=xt) -> z_tgt_private @ 2*B*D
    // task 2: ca     (x=xs,y=xt) -> z_shared      @ 0
    const float* xq_g = (task == 1) ? (x_tgt + b * SS) : (x_src + b * SS);
    const float* y_g  = (task == 0) ? (x_src + b * SS) : (x_tgt + b * SS);
    const int type    = (task == 2) ? 1 : 0;
    const float* in_w  = type ? ca_in_w  : sa_in_w;
    const float* in_b  = type ? ca_in_b  : sa_in_b;
    const float* out_w = type ? ca_out_w : sa_out_w;
    const float* out_b = type ? ca_out_b : sa_out_b;
    const float* g     = type ? ca_ln_g  : sa_ln_g;
    const float* lb    = type ? ca_ln_b  : sa_ln_b;
    const int out_base = ((task == 0) ? BB * DD : (task == 1) ? 2 * BB * DD : 0) + b * DD;

    __shared__ float sv[6][DD];        // aq,ak,av,cq,ck,cv
    __shared__ float cvec[3][DD];      // centered pw / u / e  (stage2 parks u,e here)
    __shared__ float cst[8];           // alpha,gamma,G11,G22,G33,G12,G13,G23
    __shared__ __align__(16) float ys_l[SS];
    __shared__ float rmax[8], rmin[8], rP[8], rT[8], rI[8];
    __shared__ float bc[5];            // ymax,ymin,P,T,I

    const int wave = tid >> 6, lane = tid & 63;

    // issue main-phase global loads early
    const float xq = xq_g[tid];
    const float y  = y_g[tid];
    ys_l[tid] = y;

    // per-wave y max/min (for stable exp)
    {
        float mx = y, mn = y;
        #pragma unroll
        for (int o = 32; o > 0; o >>= 1) {
            mx = fmaxf(mx, __shfl_down(mx, o));
            mn = fminf(mn, __shfl_down(mn, o));
        }
        if (lane == 0) { rmax[wave] = mx; rmin[wave] = mn; }
    }

    // ---- prep stage 1: 6 matvecs {q,k,v} x {pw,pb} (384 threads) ----
    if (tid < 384) {
        const int mat = tid >> 6, d = tid & 63;
        const int rb = mat % 3, vecsel = mat / 3;
        const float* W = in_w + (rb * DD + d) * DD;
        const float* v = vecsel ? proj_b : proj_w;
        float s = 0.f;
        #pragma unroll
        for (int e = 0; e < DD; e += 4) {
            float4 wv = *(const float4*)(W + e);
            float4 vv = *(const float4*)(v + e);
            s += wv.x * vv.x + wv.y * vv.y + wv.z * vv.z + wv.w * vv.w;
        }
        if (vecsel) s += in_b[rb * DD + d];
        sv[mat][d] = s;
    }
    __syncthreads();

    // ---- stage 2: u = Wo@av ; e = pb + Wo@cv + bo (128 threads) ----
    if (tid < 128) {
        const int which = tid >> 6, d = tid & 63;
        const float* W = out_w + d * DD;
        const float* v = sv[which ? 5 : 2];   // cv : av
        float s = 0.f;
        #pragma unroll
        for (int e = 0; e < DD; e += 4) {
            float4 wv = *(const float4*)(W + e);
            s += wv.x * v[e] + wv.y * v[e + 1] + wv.z * v[e + 2] + wv.w * v[e + 3];
        }
        if (which) cvec[2][d] = proj_b[d] + s + out_b[d];  // e (uncentered)
        else       cvec[1][d] = s;                          // u (uncentered)
    }
    // block-combine y max/min (wave 7, parallel with stage 2)
    if (tid == 511) {
        float a = rmax[0], m = rmin[0];
        #pragma unroll
        for (int i = 1; i < 8; ++i) { a = fmaxf(a, rmax[i]); m = fminf(m, rmin[i]); }
        bc[0] = a; bc[1] = m;
    }
    __syncthreads();

    // ---- stage 3: scalars + Gram + centering (wave 0) ----
    if (wave == 0) {
        auto wred = [](float x) {
            #pragma unroll
            for (int o = 32; o > 0; o >>= 1) x += __shfl_down(x, o);
            return __shfl(x, 0);
        };
        const float aq = sv[0][lane], ak = sv[1][lane], cq = sv[3][lane];
        const float pw = proj_w[lane];
        const float u  = cvec[1][lane], e = cvec[2][lane];

        const float alpha = wred(aq * ak) * 0.125f;   // /sqrt(64)
        const float gamma = wred(cq * ak) * 0.125f;
        const float m_pw = wred(pw) * (1.f / DD);
        const float m_u  = wred(u)  * (1.f / DD);
        const float m_e  = wred(e)  * (1.f / DD);
        const float a  = pw - m_pw;
        const float bb = u  - m_u;
        const float c  = e  - m_e;
        const float G11 = wred(a * a)   * (1.f / DD);
        const float G22 = wred(bb * bb) * (1.f / DD);
        const float G33 = wred(c * c)   * (1.f / DD);
        const float G12 = wred(a * bb)  * (1.f / DD);
        const float G13 = wred(a * c)   * (1.f / DD);
        const float G23 = wred(bb * c)  * (1.f / DD);

        cvec[0][lane] = a; cvec[1][lane] = bb; cvec[2][lane] = c;
        if (lane == 0) {
            cst[0] = alpha; cst[1] = gamma;
            cst[2] = G11; cst[3] = G22; cst[4] = G33;
            cst[5] = G12; cst[6] = G13; cst[7] = G23;
        }
    }
    __syncthreads();

    const float ymax = bc[0], ymin = bc[1];
    const float alpha = cst[0], gamma = cst[1];
    const float G11 = cst[2], G22 = cst[3], G33 = cst[4];
    const float G12 = cst[5], G13 = cst[6], G23 = cst[7];

    const float c   = alpha * xq + gamma;
    const float clf = c * L2E;
    const float nml = -fmaxf(c * ymax, c * ymin) * L2E;   // arg = clf*y + nml <= 0
    const v2f cl = { clf, clf };
    const v2f nm = { nml, nml };

    v2f den = { 0.f, 0.f }, num = { 0.f, 0.f };
    #pragma unroll 4
    for (int k = 0; k < SS; k += 8) {
        float4 ya = *(const float4*)&ys_l[k];
        float4 yb = *(const float4*)&ys_l[k + 4];
        v2f y0 = { ya.x, ya.y }, y1 = { ya.z, ya.w };
        v2f y2 = { yb.x, yb.y }, y3 = { yb.z, yb.w };
        v2f a0 = cl * y0 + nm;
        v2f a1 = cl * y1 + nm;
        v2f a2 = cl * y2 + nm;
        v2f a3 = cl * y3 + nm;
        v2f E0 = { fexp2(a0.x), fexp2(a0.y) };
        v2f E1 = { fexp2(a1.x), fexp2(a1.y) };
        v2f E2 = { fexp2(a2.x), fexp2(a2.y) };
        v2f E3 = { fexp2(a3.x), fexp2(a3.y) };
        den += E0; num += y0 * E0;
        den += E1; num += y1 * E1;
        den += E2; num += y2 * E2;
        den += E3; num += y3 * E3;
    }
    const float t = (num.x + num.y) / (den.x + den.y);

    const float var = xq * xq * G11 + t * t * G22 + G33
                    + 2.f * (xq * t * G12 + xq * G13 + t * G23);
    const float inv = rsqrtf(var + LN_EPS);

    float pP = xq * inv, pT = t * inv, pI = inv;
    #pragma unroll
    for (int o = 32; o > 0; o >>= 1) {
        pP += __shfl_down(pP, o);
        pT += __shfl_down(pT, o);
        pI += __shfl_down(pI, o);
    }
    if (lane == 0) { rP[wave] = pP; rT[wave] = pT; rI[wave] = pI; }
    __syncthreads();
    if (tid == 0) {
        float sP = 0.f, sT = 0.f, sI = 0.f;
        #pragma unroll
        for (int i = 0; i < 8; ++i) { sP += rP[i]; sT += rT[i]; sI += rI[i]; }
        bc[2] = sP * (1.f / SS); bc[3] = sT * (1.f / SS); bc[4] = sI * (1.f / SS);
    }
    __syncthreads();

    if (tid < DD) {
        const float P = bc[2], T = bc[3], I = bc[4];
        float z = (P * cvec[0][tid] + T * cvec[1][tid] + I * cvec[2][tid]) * g[tid] + lb[tid];
        out[out_base + tid] = z;
    }
}

extern "C" void kernel_launch(void* const* d_in, const int* in_sizes, int n_in,
                              void* d_out, int out_size, void* d_ws, size_t ws_size,
                              hipStream_t stream) {
    const float* x_src    = (const float*)d_in[0];
    const float* x_tgt    = (const float*)d_in[1];
    const float* proj_w   = (const float*)d_in[2];
    const float* proj_b   = (const float*)d_in[3];
    const float* sa_in_w  = (const float*)d_in[4];
    const float* sa_in_b  = (const float*)d_in[5];
    const float* sa_out_w = (const float*)d_in[6];
    const float* sa_out_b = (const float*)d_in[7];
    const float* sa_ln_g  = (const float*)d_in[8];
    const float* sa_ln_b  = (const float*)d_in[9];
    const float* ca_in_w  = (const float*)d_in[10];
    const float* ca_in_b  = (const float*)d_in[11];
    const float* ca_out_w = (const float*)d_in[12];
    const float* ca_out_b = (const float*)d_in[13];
    const float* ca_ln_g  = (const float*)d_in[14];
    const float* ca_ln_b  = (const float*)d_in[15];
    float* out = (float*)d_out;

    fused_kernel<<<BB * 3, 512, 0, stream>>>(
        x_src, x_tgt, proj_w, proj_b,
        sa_in_w, sa_in_b, sa_out_w, sa_out_b, sa_ln_g, sa_ln_b,
        ca_in_w, ca_in_b, ca_out_w, ca_out_b, ca_ln_g, ca_ln_b,
        out);
}